// Round 4
// baseline (359.983 us; speedup 1.0000x reference)
//
#include <hip/hip_runtime.h>
#include <hip/hip_bf16.h>

#define D 128
#define XSTRIDE 68   // 256B+16B row pitch: wave's 4 row-groups land in distinct bank quads

// ---------------------------------------------------------------- count edges
__global__ __launch_bounds__(256) void count_edges(const int* __restrict__ col,
                                                   int* __restrict__ cnt, int E) {
    int t = blockIdx.x * blockDim.x + threadIdx.x;
    if (t < E) atomicAdd(&cnt[col[t]], 1);
}

// ------------------------------------------- scan phase A: block partial sums
__global__ __launch_bounds__(256) void scan_partial(const int* __restrict__ cnt,
                                                    float* __restrict__ dis,
                                                    int* __restrict__ bsum, int N) {
    int i = blockIdx.x * 256 + threadIdx.x;
    int v = 0;
    if (i < N) {
        v = cnt[i] + 1;
        dis[i] = rsqrtf((float)v);
    }
    int s = v;
#pragma unroll
    for (int d = 1; d < 64; d <<= 1) s += __shfl_xor(s, d);
    __shared__ int ws[4];
    int lane = threadIdx.x & 63, w = threadIdx.x >> 6;
    if (lane == 0) ws[w] = s;
    __syncthreads();
    if (threadIdx.x == 0) bsum[blockIdx.x] = ws[0] + ws[1] + ws[2] + ws[3];
}

// --------------------------------- scan phase B: exclusive scan of block sums
__global__ __launch_bounds__(256) void scan_blocksums(const int* __restrict__ bsum,
                                                      int* __restrict__ boff, int nb) {
    int t = threadIdx.x;
    int v = (t < nb) ? bsum[t] : 0;
    int lane = t & 63, w = t >> 6;
    int sc = v;
#pragma unroll
    for (int d = 1; d < 64; d <<= 1) {
        int y = __shfl_up(sc, d);
        if (lane >= d) sc += y;
    }
    __shared__ int ws[4];
    if (lane == 63) ws[w] = sc;
    __syncthreads();
    int add = 0;
    for (int j = 0; j < w; ++j) add += ws[j];
    if (t < nb) boff[t] = add + sc - v;
}

// ------------------------------- scan phase C: final offsets (off and cursor)
__global__ __launch_bounds__(256) void scan_final(const int* __restrict__ cnt,
                                                  const int* __restrict__ boff,
                                                  int* __restrict__ off,
                                                  int* __restrict__ cursor,
                                                  int N, int Etot) {
    int i = blockIdx.x * 256 + threadIdx.x;
    int v = (i < N) ? cnt[i] + 1 : 0;
    int lane = threadIdx.x & 63, w = threadIdx.x >> 6;
    int sc = v;
#pragma unroll
    for (int d = 1; d < 64; d <<= 1) {
        int y = __shfl_up(sc, d);
        if (lane >= d) sc += y;
    }
    __shared__ int ws[4];
    if (lane == 63) ws[w] = sc;
    __syncthreads();
    int add = boff[blockIdx.x];
    for (int j = 0; j < w; ++j) add += ws[j];
    int ex = add + sc - v;
    if (i < N) {
        off[i] = ex;
        cursor[i] = ex;
    }
    if (i == 0 && blockIdx.x == 0) off[N] = Etot;
}

// ----------------------------------------------------------------- CSR fill
__global__ __launch_bounds__(256) void fill_edges(const int* __restrict__ row,
                                                  const int* __restrict__ col,
                                                  const float* __restrict__ dis,
                                                  int* __restrict__ cursor,
                                                  int* __restrict__ eidx,
                                                  float* __restrict__ enrm,
                                                  int E, int N) {
    int t = blockIdx.x * blockDim.x + threadIdx.x;
    if (t < E) {
        int r = row[t], c = col[t];
        int p = atomicAdd(&cursor[c], 1);
        eidx[p] = r;
        enrm[p] = dis[r] * dis[c];
    } else if (t < E + N) {
        int i = t - E;
        int p = atomicAdd(&cursor[i], 1);
        eidx[p] = i;
        float dd = dis[i];
        enrm[p] = dd * dd;
    }
}

// ------------------------------------------------------------- dense GEMM 128
// 512 thr (8 waves), 256 rows/block, per-thread 8 rows x 8 cols.
__global__ __launch_bounds__(512, 2) void gemm_tile(const float* __restrict__ X,
                                                    const float* __restrict__ W,
                                                    float* __restrict__ H, int N) {
    __shared__ float Wl[128 * 128];        // 64 KB, row-major [k][c]
    __shared__ float Xl[256 * XSTRIDE];    // 68 KB, [row][k-within-half]
    const int t = threadIdx.x;
    const int rbase = blockIdx.x * 256;

    for (int i = t; i < 4096; i += 512)
        *(float4*)&Wl[i * 4] = ((const float4*)W)[i];

    const int cg = t & 15;
    const int rg = t >> 4;
    float acc[8][8];
#pragma unroll
    for (int i = 0; i < 8; ++i)
#pragma unroll
        for (int j = 0; j < 8; ++j) acc[i][j] = 0.f;

    for (int half = 0; half < 2; ++half) {
        __syncthreads();
        for (int i = t; i < 4096; i += 512) {
            int r = i >> 4;
            int k2 = (i & 15) << 2;
            int gr = rbase + r;
            float4 v;
            if (gr < N) v = *(const float4*)&X[(size_t)gr * D + half * 64 + k2];
            else { v.x = v.y = v.z = v.w = 0.f; }
            *(float4*)&Xl[r * XSTRIDE + k2] = v;
        }
        __syncthreads();

        for (int k = 0; k < 64; k += 4) {
            const int kb = half * 64 + k;
            float4 wv0[4], wv1[4];
#pragma unroll
            for (int kk = 0; kk < 4; ++kk) {
                wv0[kk] = *(const float4*)&Wl[(kb + kk) * D + cg * 4];
                wv1[kk] = *(const float4*)&Wl[(kb + kk) * D + 64 + cg * 4];
            }
#pragma unroll
            for (int i = 0; i < 8; ++i) {
                float4 xv = *(const float4*)&Xl[(rg + 32 * i) * XSTRIDE + k];
                acc[i][0] += xv.x * wv0[0].x + xv.y * wv0[1].x + xv.z * wv0[2].x + xv.w * wv0[3].x;
                acc[i][1] += xv.x * wv0[0].y + xv.y * wv0[1].y + xv.z * wv0[2].y + xv.w * wv0[3].y;
                acc[i][2] += xv.x * wv0[0].z + xv.y * wv0[1].z + xv.z * wv0[2].z + xv.w * wv0[3].z;
                acc[i][3] += xv.x * wv0[0].w + xv.y * wv0[1].w + xv.z * wv0[2].w + xv.w * wv0[3].w;
                acc[i][4] += xv.x * wv1[0].x + xv.y * wv1[1].x + xv.z * wv1[2].x + xv.w * wv1[3].x;
                acc[i][5] += xv.x * wv1[0].y + xv.y * wv1[1].y + xv.z * wv1[2].y + xv.w * wv1[3].y;
                acc[i][6] += xv.x * wv1[0].z + xv.y * wv1[1].z + xv.z * wv1[2].z + xv.w * wv1[3].z;
                acc[i][7] += xv.x * wv1[0].w + xv.y * wv1[1].w + xv.z * wv1[2].w + xv.w * wv1[3].w;
            }
        }
    }

#pragma unroll
    for (int i = 0; i < 8; ++i) {
        int r = rbase + rg + 32 * i;
        if (r < N) {
            float4 o0, o1;
            o0.x = acc[i][0]; o0.y = acc[i][1]; o0.z = acc[i][2]; o0.w = acc[i][3];
            o1.x = acc[i][4]; o1.y = acc[i][5]; o1.z = acc[i][6]; o1.w = acc[i][7];
            *(float4*)&H[(size_t)r * D + cg * 4]      = o0;
            *(float4*)&H[(size_t)r * D + 64 + cg * 4] = o1;
        }
    }
}

// --------------------------------------------------------- SpMM + bias + ReLU
// Feature-sliced, XCD-affine: slice = blockIdx % 8 (16 features), so each
// XCD's gather working set is H[:, slice*16..slice*16+15] = 3.2 MB < 4 MB L2.
// Block: 256 thr = 16 targets x 16 features.
__global__ __launch_bounds__(256) void spmm_sliced(const float* __restrict__ H,
                                                   const int* __restrict__ off,
                                                   const int* __restrict__ eidx,
                                                   const float* __restrict__ enrm,
                                                   const float* __restrict__ bias,
                                                   float* __restrict__ O, int N) {
    const int slice = blockIdx.x & 7;
    const int tg    = blockIdx.x >> 3;
    const int tl    = threadIdx.x >> 4;      // local target 0..15
    const int f     = threadIdx.x & 15;      // feature within slice
    const int c     = tg * 16 + tl;
    if (c >= N) return;
    const int d = slice * 16 + f;
    const int s = off[c], e = off[c + 1];
    float acc = bias[d];
    int k = s;
    for (; k + 4 <= e; k += 4) {
        int r0 = eidx[k],     r1 = eidx[k + 1];
        int r2 = eidx[k + 2], r3 = eidx[k + 3];
        float w0 = enrm[k],     w1 = enrm[k + 1];
        float w2 = enrm[k + 2], w3 = enrm[k + 3];
        float h0 = H[(size_t)r0 * D + d], h1 = H[(size_t)r1 * D + d];
        float h2 = H[(size_t)r2 * D + d], h3 = H[(size_t)r3 * D + d];
        acc += h0 * w0; acc += h1 * w1; acc += h2 * w2; acc += h3 * w3;
    }
    for (; k < e; ++k) acc += H[(size_t)eidx[k] * D + d] * enrm[k];
    O[(size_t)c * D + d] = fmaxf(acc, 0.f);
}

// ----------------------------------------------------------------- head GEMV
__global__ __launch_bounds__(256) void head_kernel(const float* __restrict__ H,
                                                   const float* __restrict__ Wh,
                                                   const float* __restrict__ bh,
                                                   float* __restrict__ out, int N) {
    int gt = blockIdx.x * blockDim.x + threadIdx.x;
    int wid = gt >> 6;
    int lane = gt & 63;
    if (wid >= N) return;
    const float* hrow = H + (size_t)wid * D;
    float x0 = hrow[lane], x1 = hrow[lane + 64];
    float a0 = x0 * Wh[lane * 3 + 0] + x1 * Wh[(lane + 64) * 3 + 0];
    float a1 = x0 * Wh[lane * 3 + 1] + x1 * Wh[(lane + 64) * 3 + 1];
    float a2 = x0 * Wh[lane * 3 + 2] + x1 * Wh[(lane + 64) * 3 + 2];
#pragma unroll
    for (int s = 32; s > 0; s >>= 1) {
        a0 += __shfl_down(a0, s);
        a1 += __shfl_down(a1, s);
        a2 += __shfl_down(a2, s);
    }
    if (lane == 0) {
        out[wid * 3 + 0] = a0 + bh[0];
        out[wid * 3 + 1] = a1 + bh[1];
        out[wid * 3 + 2] = a2 + bh[2];
    }
}

// ---------------------------------------------------------------------------
extern "C" void kernel_launch(void* const* d_in, const int* in_sizes, int n_in,
                              void* d_out, int out_size, void* d_ws, size_t ws_size,
                              hipStream_t stream) {
    const float* x  = (const float*)d_in[0];
    const int*   ei = (const int*)d_in[1];
    const float* W1 = (const float*)d_in[2];
    const float* b1 = (const float*)d_in[3];
    const float* W2 = (const float*)d_in[4];
    const float* b2 = (const float*)d_in[5];
    const float* Wh = (const float*)d_in[6];
    const float* bh = (const float*)d_in[7];
    float* out = (float*)d_out;

    const int N = in_sizes[0] / D;       // 50000
    const int E = in_sizes[1] / 2;       // 800000
    const int Etot = E + N;
    const int* row = ei;
    const int* col = ei + E;

    // -------- workspace layout
    char* ws = (char*)d_ws;
    size_t o = 0;
    auto alloc = [&](size_t bytes) -> char* {
        char* p = ws + o;
        o = (o + bytes + 255) & ~(size_t)255;
        return p;
    };
    const int nb = (N + 255) / 256;
    int*   cnt    = (int*)  alloc((size_t)N * 4);
    int*   off    = (int*)  alloc((size_t)(N + 1) * 4);
    int*   cursor = (int*)  alloc((size_t)N * 4);
    float* dis    = (float*)alloc((size_t)N * 4);
    int*   bsum   = (int*)  alloc((size_t)nb * 4);
    int*   boff   = (int*)  alloc((size_t)nb * 4);
    int*   eidx   = (int*)  alloc((size_t)Etot * 4);
    float* enrm   = (float*)alloc((size_t)Etot * 4);
    float* A      = (float*)alloc((size_t)N * D * 4);
    float* B      = (float*)alloc((size_t)N * D * 4);
    (void)ws_size;

    hipMemsetAsync(cnt, 0, (size_t)N * 4, stream);
    count_edges<<<(E + 255) / 256, 256, 0, stream>>>(col, cnt, E);
    scan_partial<<<nb, 256, 0, stream>>>(cnt, dis, bsum, N);
    scan_blocksums<<<1, 256, 0, stream>>>(bsum, boff, nb);
    scan_final<<<nb, 256, 0, stream>>>(cnt, boff, off, cursor, N, Etot);
    fill_edges<<<(Etot + 255) / 256, 256, 0, stream>>>(row, col, dis, cursor,
                                                       eidx, enrm, E, N);

    const int gblocks = (N + 255) / 256;           // 256 rows per block
    const int sblocks = ((N + 15) / 16) * 8;       // 16 targets x 8 slices
    gemm_tile<<<gblocks, 512, 0, stream>>>(x, W1, A, N);
    spmm_sliced<<<sblocks, 256, 0, stream>>>(A, off, eidx, enrm, b1, B, N);
    gemm_tile<<<gblocks, 512, 0, stream>>>(B, W2, A, N);
    spmm_sliced<<<sblocks, 256, 0, stream>>>(A, off, eidx, enrm, b2, B, N);
    head_kernel<<<((size_t)N * 64 + 255) / 256, 256, 0, stream>>>(B, Wh, bh, out, N);
}

// Round 5
// 284.188 us; speedup vs baseline: 1.2667x; 1.2667x over previous
//
#include <hip/hip_runtime.h>
#include <hip/hip_bf16.h>

#define D 128
#define XSTRIDE 68   // 256B+16B row pitch: wave's 4 row-groups land in distinct bank quads

// ---------------------------------------------------------------- count edges
__global__ __launch_bounds__(256) void count_edges(const int* __restrict__ col,
                                                   int* __restrict__ cnt, int E) {
    int t = blockIdx.x * blockDim.x + threadIdx.x;
    if (t < E) atomicAdd(&cnt[col[t]], 1);
}

// ------------------------------------------- scan phase A: block partial sums
__global__ __launch_bounds__(256) void scan_partial(const int* __restrict__ cnt,
                                                    float* __restrict__ dis,
                                                    int* __restrict__ bsum, int N) {
    int i = blockIdx.x * 256 + threadIdx.x;
    int v = 0;
    if (i < N) {
        v = cnt[i] + 1;
        dis[i] = rsqrtf((float)v);
    }
    int s = v;
#pragma unroll
    for (int d = 1; d < 64; d <<= 1) s += __shfl_xor(s, d);
    __shared__ int ws[4];
    int lane = threadIdx.x & 63, w = threadIdx.x >> 6;
    if (lane == 0) ws[w] = s;
    __syncthreads();
    if (threadIdx.x == 0) bsum[blockIdx.x] = ws[0] + ws[1] + ws[2] + ws[3];
}

// --------------------------------- scan phase B: exclusive scan of block sums
__global__ __launch_bounds__(256) void scan_blocksums(const int* __restrict__ bsum,
                                                      int* __restrict__ boff, int nb) {
    int t = threadIdx.x;
    int v = (t < nb) ? bsum[t] : 0;
    int lane = t & 63, w = t >> 6;
    int sc = v;
#pragma unroll
    for (int d = 1; d < 64; d <<= 1) {
        int y = __shfl_up(sc, d);
        if (lane >= d) sc += y;
    }
    __shared__ int ws[4];
    if (lane == 63) ws[w] = sc;
    __syncthreads();
    int add = 0;
    for (int j = 0; j < w; ++j) add += ws[j];
    if (t < nb) boff[t] = add + sc - v;
}

// ------------------------------- scan phase C: final offsets (off and cursor)
__global__ __launch_bounds__(256) void scan_final(const int* __restrict__ cnt,
                                                  const int* __restrict__ boff,
                                                  int* __restrict__ off,
                                                  int* __restrict__ cursor,
                                                  int N, int Etot) {
    int i = blockIdx.x * 256 + threadIdx.x;
    int v = (i < N) ? cnt[i] + 1 : 0;
    int lane = threadIdx.x & 63, w = threadIdx.x >> 6;
    int sc = v;
#pragma unroll
    for (int d = 1; d < 64; d <<= 1) {
        int y = __shfl_up(sc, d);
        if (lane >= d) sc += y;
    }
    __shared__ int ws[4];
    if (lane == 63) ws[w] = sc;
    __syncthreads();
    int add = boff[blockIdx.x];
    for (int j = 0; j < w; ++j) add += ws[j];
    int ex = add + sc - v;
    if (i < N) {
        off[i] = ex;
        cursor[i] = ex;
    }
    if (i == 0 && blockIdx.x == 0) off[N] = Etot;
}

// ----------------------------------------------------------------- CSR fill
__global__ __launch_bounds__(256) void fill_edges(const int* __restrict__ row,
                                                  const int* __restrict__ col,
                                                  const float* __restrict__ dis,
                                                  int* __restrict__ cursor,
                                                  int* __restrict__ eidx,
                                                  float* __restrict__ enrm,
                                                  int E, int N) {
    int t = blockIdx.x * blockDim.x + threadIdx.x;
    if (t < E) {
        int r = row[t], c = col[t];
        int p = atomicAdd(&cursor[c], 1);
        eidx[p] = r;
        enrm[p] = dis[r] * dis[c];
    } else if (t < E + N) {
        int i = t - E;
        int p = atomicAdd(&cursor[i], 1);
        eidx[p] = i;
        float dd = dis[i];
        enrm[p] = dd * dd;
    }
}

// ------------------------------------------------------------- dense GEMM 128
// H[N,128] = X[N,128] @ W[128,128].
// 512 thr (8 waves), 128 rows/block, per-thread 4 rows x 8 cols.
// LDS: W one k-half (32 KB) + X tile (34.8 KB) = 66.8 KB -> 2 blocks/CU,
// 16 waves/CU (4/SIMD).  cg = t&15 owns cols {4cg..4cg+3} u {64+4cg..};
// rg = t>>4 owns rows {rg+32i} (pitch 68 -> distinct bank quads).
__global__ __launch_bounds__(512, 4) void gemm_tile(const float* __restrict__ X,
                                                    const float* __restrict__ W,
                                                    float* __restrict__ H, int N) {
    __shared__ float Wl[64 * 128];         // 32 KB: one k-half, row-major [k][c]
    __shared__ float Xl[128 * XSTRIDE];    // 34.8 KB
    const int t = threadIdx.x;
    const int rbase = blockIdx.x * 128;
    const int cg = t & 15;
    const int rg = t >> 4;

    float acc[4][8];
#pragma unroll
    for (int i = 0; i < 4; ++i)
#pragma unroll
        for (int j = 0; j < 8; ++j) acc[i][j] = 0.f;

    for (int half = 0; half < 2; ++half) {
        __syncthreads();   // prev-half reads done before overwrite
        // stage W k-half: 64 rows x 32 float4 = 2048 float4, 4 per thread
        for (int i = t; i < 2048; i += 512) {
            int kr = i >> 5, c4 = (i & 31) << 2;
            *(float4*)&Wl[kr * 128 + c4] =
                *(const float4*)&W[(size_t)(half * 64 + kr) * 128 + c4];
        }
        // stage X tile: 128 rows x 16 float4 = 2048 float4
        for (int i = t; i < 2048; i += 512) {
            int r = i >> 4, k2 = (i & 15) << 2;
            int gr = rbase + r;
            float4 v;
            if (gr < N) v = *(const float4*)&X[(size_t)gr * D + half * 64 + k2];
            else { v.x = v.y = v.z = v.w = 0.f; }
            *(float4*)&Xl[r * XSTRIDE + k2] = v;
        }
        __syncthreads();

        for (int k = 0; k < 64; k += 4) {
            float4 wv0[4], wv1[4];
#pragma unroll
            for (int kk = 0; kk < 4; ++kk) {
                wv0[kk] = *(const float4*)&Wl[(k + kk) * 128 + cg * 4];
                wv1[kk] = *(const float4*)&Wl[(k + kk) * 128 + 64 + cg * 4];
            }
#pragma unroll
            for (int i = 0; i < 4; ++i) {
                float4 xv = *(const float4*)&Xl[(rg + 32 * i) * XSTRIDE + k];
                acc[i][0] += xv.x * wv0[0].x + xv.y * wv0[1].x + xv.z * wv0[2].x + xv.w * wv0[3].x;
                acc[i][1] += xv.x * wv0[0].y + xv.y * wv0[1].y + xv.z * wv0[2].y + xv.w * wv0[3].y;
                acc[i][2] += xv.x * wv0[0].z + xv.y * wv0[1].z + xv.z * wv0[2].z + xv.w * wv0[3].z;
                acc[i][3] += xv.x * wv0[0].w + xv.y * wv0[1].w + xv.z * wv0[2].w + xv.w * wv0[3].w;
                acc[i][4] += xv.x * wv1[0].x + xv.y * wv1[1].x + xv.z * wv1[2].x + xv.w * wv1[3].x;
                acc[i][5] += xv.x * wv1[0].y + xv.y * wv1[1].y + xv.z * wv1[2].y + xv.w * wv1[3].y;
                acc[i][6] += xv.x * wv1[0].z + xv.y * wv1[1].z + xv.z * wv1[2].z + xv.w * wv1[3].z;
                acc[i][7] += xv.x * wv1[0].w + xv.y * wv1[1].w + xv.z * wv1[2].w + xv.w * wv1[3].w;
            }
        }
    }

#pragma unroll
    for (int i = 0; i < 4; ++i) {
        int r = rbase + rg + 32 * i;
        if (r < N) {
            float4 o0, o1;
            o0.x = acc[i][0]; o0.y = acc[i][1]; o0.z = acc[i][2]; o0.w = acc[i][3];
            o1.x = acc[i][4]; o1.y = acc[i][5]; o1.z = acc[i][6]; o1.w = acc[i][7];
            *(float4*)&H[(size_t)r * D + cg * 4]      = o0;
            *(float4*)&H[(size_t)r * D + 64 + cg * 4] = o1;
        }
    }
}

// --------------------------------------------------------- SpMM + bias + ReLU
// Full-row gather (>= one 128B line per segment).  One wave per target node;
// lane owns 2 features (float2), so one edge = ONE 512B gather per wave.
// 8-deep edge unroll for outstanding-load ILP.  No __syncthreads.
__global__ __launch_bounds__(256) void spmm_row(const float* __restrict__ H,
                                                const int* __restrict__ off,
                                                const int* __restrict__ eidx,
                                                const float* __restrict__ enrm,
                                                const float* __restrict__ bias,
                                                float* __restrict__ O, int N) {
    const int c = blockIdx.x * 4 + (threadIdx.x >> 6);
    if (c >= N) return;
    const int lane = threadIdx.x & 63;
    const int d0 = lane * 2;
    const int s = off[c], e = off[c + 1];
    float ax = bias[d0], ay = bias[d0 + 1];
    int k = s;
    for (; k + 8 <= e; k += 8) {
        int r[8];
#pragma unroll
        for (int j = 0; j < 8; ++j) r[j] = eidx[k + j];
        float2 h[8];
        float  w[8];
#pragma unroll
        for (int j = 0; j < 8; ++j) {
            h[j] = *(const float2*)&H[(size_t)r[j] * D + d0];
            w[j] = enrm[k + j];
        }
#pragma unroll
        for (int j = 0; j < 8; ++j) {
            ax += h[j].x * w[j];
            ay += h[j].y * w[j];
        }
    }
    for (; k + 2 <= e; k += 2) {
        int r0 = eidx[k], r1 = eidx[k + 1];
        float w0 = enrm[k], w1 = enrm[k + 1];
        float2 h0 = *(const float2*)&H[(size_t)r0 * D + d0];
        float2 h1 = *(const float2*)&H[(size_t)r1 * D + d0];
        ax += h0.x * w0 + h1.x * w1;
        ay += h0.y * w0 + h1.y * w1;
    }
    if (k < e) {
        float2 h0 = *(const float2*)&H[(size_t)eidx[k] * D + d0];
        float w0 = enrm[k];
        ax += h0.x * w0;
        ay += h0.y * w0;
    }
    float2 o;
    o.x = fmaxf(ax, 0.f);
    o.y = fmaxf(ay, 0.f);
    *(float2*)&O[(size_t)c * D + d0] = o;
}

// ----------------------------------------------------------------- head GEMV
__global__ __launch_bounds__(256) void head_kernel(const float* __restrict__ H,
                                                   const float* __restrict__ Wh,
                                                   const float* __restrict__ bh,
                                                   float* __restrict__ out, int N) {
    int gt = blockIdx.x * blockDim.x + threadIdx.x;
    int wid = gt >> 6;
    int lane = gt & 63;
    if (wid >= N) return;
    const float* hrow = H + (size_t)wid * D;
    float x0 = hrow[lane], x1 = hrow[lane + 64];
    float a0 = x0 * Wh[lane * 3 + 0] + x1 * Wh[(lane + 64) * 3 + 0];
    float a1 = x0 * Wh[lane * 3 + 1] + x1 * Wh[(lane + 64) * 3 + 1];
    float a2 = x0 * Wh[lane * 3 + 2] + x1 * Wh[(lane + 64) * 3 + 2];
#pragma unroll
    for (int s = 32; s > 0; s >>= 1) {
        a0 += __shfl_down(a0, s);
        a1 += __shfl_down(a1, s);
        a2 += __shfl_down(a2, s);
    }
    if (lane == 0) {
        out[wid * 3 + 0] = a0 + bh[0];
        out[wid * 3 + 1] = a1 + bh[1];
        out[wid * 3 + 2] = a2 + bh[2];
    }
}

// ---------------------------------------------------------------------------
extern "C" void kernel_launch(void* const* d_in, const int* in_sizes, int n_in,
                              void* d_out, int out_size, void* d_ws, size_t ws_size,
                              hipStream_t stream) {
    const float* x  = (const float*)d_in[0];
    const int*   ei = (const int*)d_in[1];
    const float* W1 = (const float*)d_in[2];
    const float* b1 = (const float*)d_in[3];
    const float* W2 = (const float*)d_in[4];
    const float* b2 = (const float*)d_in[5];
    const float* Wh = (const float*)d_in[6];
    const float* bh = (const float*)d_in[7];
    float* out = (float*)d_out;

    const int N = in_sizes[0] / D;       // 50000
    const int E = in_sizes[1] / 2;       // 800000
    const int Etot = E + N;
    const int* row = ei;
    const int* col = ei + E;

    // -------- workspace layout
    char* ws = (char*)d_ws;
    size_t o = 0;
    auto alloc = [&](size_t bytes) -> char* {
        char* p = ws + o;
        o = (o + bytes + 255) & ~(size_t)255;
        return p;
    };
    const int nb = (N + 255) / 256;
    int*   cnt    = (int*)  alloc((size_t)N * 4);
    int*   off    = (int*)  alloc((size_t)(N + 1) * 4);
    int*   cursor = (int*)  alloc((size_t)N * 4);
    float* dis    = (float*)alloc((size_t)N * 4);
    int*   bsum   = (int*)  alloc((size_t)nb * 4);
    int*   boff   = (int*)  alloc((size_t)nb * 4);
    int*   eidx   = (int*)  alloc((size_t)Etot * 4);
    float* enrm   = (float*)alloc((size_t)Etot * 4);
    float* A      = (float*)alloc((size_t)N * D * 4);
    float* B      = (float*)alloc((size_t)N * D * 4);
    (void)ws_size;

    hipMemsetAsync(cnt, 0, (size_t)N * 4, stream);
    count_edges<<<(E + 255) / 256, 256, 0, stream>>>(col, cnt, E);
    scan_partial<<<nb, 256, 0, stream>>>(cnt, dis, bsum, N);
    scan_blocksums<<<1, 256, 0, stream>>>(bsum, boff, nb);
    scan_final<<<nb, 256, 0, stream>>>(cnt, boff, off, cursor, N, Etot);
    fill_edges<<<(Etot + 255) / 256, 256, 0, stream>>>(row, col, dis, cursor,
                                                       eidx, enrm, E, N);

    const int gblocks = (N + 127) / 128;           // 128 rows per block
    const int sblocks = (N + 3) / 4;               // 4 targets per block
    gemm_tile<<<gblocks, 512, 0, stream>>>(x, W1, A, N);
    spmm_row<<<sblocks, 256, 0, stream>>>(A, off, eidx, enrm, b1, B, N);
    gemm_tile<<<gblocks, 512, 0, stream>>>(B, W2, A, N);
    spmm_row<<<sblocks, 256, 0, stream>>>(A, off, eidx, enrm, b2, B, N);
    head_kernel<<<((size_t)N * 64 + 255) / 256, 256, 0, stream>>>(B, Wh, bh, out, N);
}

// Round 6
// 232.064 us; speedup vs baseline: 1.5512x; 1.2246x over previous
//
#include <hip/hip_runtime.h>
#include <hip/hip_bf16.h>

#define D 128

typedef _Float16 f16;
typedef f16  f16x8 __attribute__((ext_vector_type(8)));
typedef f16  f16x2 __attribute__((ext_vector_type(2)));
typedef float f32x4 __attribute__((ext_vector_type(4)));

// ---------------------------------------------------------------- count edges
__global__ __launch_bounds__(256) void count_edges(const int* __restrict__ col,
                                                   int* __restrict__ cnt, int E) {
    int t = blockIdx.x * blockDim.x + threadIdx.x;
    if (t < E) atomicAdd(&cnt[col[t]], 1);
}

// ------------------------------------------- scan phase A: block partial sums
__global__ __launch_bounds__(256) void scan_partial(const int* __restrict__ cnt,
                                                    float* __restrict__ dis,
                                                    int* __restrict__ bsum, int N) {
    int i = blockIdx.x * 256 + threadIdx.x;
    int v = 0;
    if (i < N) {
        v = cnt[i] + 1;
        dis[i] = rsqrtf((float)v);
    }
    int s = v;
#pragma unroll
    for (int d = 1; d < 64; d <<= 1) s += __shfl_xor(s, d);
    __shared__ int ws[4];
    int lane = threadIdx.x & 63, w = threadIdx.x >> 6;
    if (lane == 0) ws[w] = s;
    __syncthreads();
    if (threadIdx.x == 0) bsum[blockIdx.x] = ws[0] + ws[1] + ws[2] + ws[3];
}

// --------------------------------- scan phase B: exclusive scan of block sums
__global__ __launch_bounds__(256) void scan_blocksums(const int* __restrict__ bsum,
                                                      int* __restrict__ boff, int nb) {
    int t = threadIdx.x;
    int v = (t < nb) ? bsum[t] : 0;
    int lane = t & 63, w = t >> 6;
    int sc = v;
#pragma unroll
    for (int d = 1; d < 64; d <<= 1) {
        int y = __shfl_up(sc, d);
        if (lane >= d) sc += y;
    }
    __shared__ int ws[4];
    if (lane == 63) ws[w] = sc;
    __syncthreads();
    int add = 0;
    for (int j = 0; j < w; ++j) add += ws[j];
    if (t < nb) boff[t] = add + sc - v;
}

// ------------------------------- scan phase C: final offsets (off and cursor)
__global__ __launch_bounds__(256) void scan_final(const int* __restrict__ cnt,
                                                  const int* __restrict__ boff,
                                                  int* __restrict__ off,
                                                  int* __restrict__ cursor,
                                                  int N, int Etot) {
    int i = blockIdx.x * 256 + threadIdx.x;
    int v = (i < N) ? cnt[i] + 1 : 0;
    int lane = threadIdx.x & 63, w = threadIdx.x >> 6;
    int sc = v;
#pragma unroll
    for (int d = 1; d < 64; d <<= 1) {
        int y = __shfl_up(sc, d);
        if (lane >= d) sc += y;
    }
    __shared__ int ws[4];
    if (lane == 63) ws[w] = sc;
    __syncthreads();
    int add = boff[blockIdx.x];
    for (int j = 0; j < w; ++j) add += ws[j];
    int ex = add + sc - v;
    if (i < N) {
        off[i] = ex;
        cursor[i] = ex;
    }
    if (i == 0 && blockIdx.x == 0) off[N] = Etot;
}

// ----------------------------------------------------------------- CSR fill
__global__ __launch_bounds__(256) void fill_edges(const int* __restrict__ row,
                                                  const int* __restrict__ col,
                                                  const float* __restrict__ dis,
                                                  int* __restrict__ cursor,
                                                  int* __restrict__ eidx,
                                                  float* __restrict__ enrm,
                                                  int E, int N) {
    int t = blockIdx.x * blockDim.x + threadIdx.x;
    if (t < E) {
        int r = row[t], c = col[t];
        int p = atomicAdd(&cursor[c], 1);
        eidx[p] = r;
        enrm[p] = dis[r] * dis[c];
    } else if (t < E + N) {
        int i = t - E;
        int p = atomicAdd(&cursor[i], 1);
        eidx[p] = i;
        float dd = dis[i];
        enrm[p] = dd * dd;
    }
}

// ---------------------------------------------- W transpose + fp16 (one-time)
// Block 0: W1 -> W1t (fp16, [n][k]);  Block 1: W2 -> W2t.
__global__ __launch_bounds__(1024) void transpose_w(const float* __restrict__ W1,
                                                    const float* __restrict__ W2,
                                                    f16* __restrict__ W1t,
                                                    f16* __restrict__ W2t) {
    const float* W = blockIdx.x ? W2 : W1;
    f16* Wt = blockIdx.x ? W2t : W1t;
    __shared__ float Wl[128 * 130];
    const int t = threadIdx.x;
    for (int i = t; i < 16384; i += 1024)
        Wl[(i >> 7) * 130 + (i & 127)] = W[i];
    __syncthreads();
    for (int i = t; i < 16384; i += 1024) {
        int n = i >> 7, k = i & 127;
        Wt[i] = (f16)Wl[k * 130 + n];
    }
}

// ----------------------------------------------------------- MFMA GEMM (fp16)
// Hh[N,128] (fp16) = X[N,128] (f32) @ W, using Wt (fp16, [n][k]).
// 256 thr = 4 waves; wave w owns rows rbase+16w..+15, all 128 cols.
// mfma_f32_16x16x32_f16: A lane: row=l&15, k=(l>>4)*8+j (8 contiguous);
// B lane: col=l&15, k=(l>>4)*8+j  (contiguous in Wt[n][k]);
// D lane: col=l&15, row=(l>>4)*4+r  (guide-verified mapping).
__global__ __launch_bounds__(256) void gemm_mfma(const float* __restrict__ X,
                                                 const f16* __restrict__ Wt,
                                                 f16* __restrict__ Hh, int N) {
    const int w = threadIdx.x >> 6, l = threadIdx.x & 63;
    const int trow = blockIdx.x * 64 + w * 16;       // tile row base
    const int arow = trow + (l & 15);                // A-frag row for this lane
    const int kg = l >> 4;                           // k-group 0..3

    f16x8 a[4];
    const float* xr = X + (size_t)arow * D;
#pragma unroll
    for (int kt = 0; kt < 4; ++kt) {
        float4 p0, p1;
        if (arow < N) {
            p0 = *(const float4*)&xr[kt * 32 + kg * 8];
            p1 = *(const float4*)&xr[kt * 32 + kg * 8 + 4];
        } else {
            p0.x = p0.y = p0.z = p0.w = 0.f;
            p1 = p0;
        }
        a[kt][0] = (f16)p0.x; a[kt][1] = (f16)p0.y;
        a[kt][2] = (f16)p0.z; a[kt][3] = (f16)p0.w;
        a[kt][4] = (f16)p1.x; a[kt][5] = (f16)p1.y;
        a[kt][6] = (f16)p1.z; a[kt][7] = (f16)p1.w;
    }

    const int drow = trow + kg * 4;                  // D rows drow..drow+3
#pragma unroll
    for (int nt = 0; nt < 8; ++nt) {
        f32x4 acc = {0.f, 0.f, 0.f, 0.f};
        const f16* wrow = Wt + (size_t)(nt * 16 + (l & 15)) * D;
#pragma unroll
        for (int kt = 0; kt < 4; ++kt) {
            f16x8 b = *(const f16x8*)&wrow[kt * 32 + kg * 8];
            acc = __builtin_amdgcn_mfma_f32_16x16x32_f16(a[kt], b, acc, 0, 0, 0);
        }
        const int dcol = nt * 16 + (l & 15);
#pragma unroll
        for (int r = 0; r < 4; ++r) {
            int orow = drow + r;
            if (orow < N) Hh[(size_t)orow * D + dcol] = (f16)acc[r];
        }
    }
}

// --------------------------------------------------------- SpMM + bias + ReLU
// Gathers fp16 H rows (256 B per edge per wave = 2 full lines), accumulates
// f32, writes f32.  One wave per target; lane owns 2 features.
__global__ __launch_bounds__(256) void spmm_row(const f16* __restrict__ Hh,
                                                const int* __restrict__ off,
                                                const int* __restrict__ eidx,
                                                const float* __restrict__ enrm,
                                                const float* __restrict__ bias,
                                                float* __restrict__ O, int N) {
    const int c = blockIdx.x * 4 + (threadIdx.x >> 6);
    if (c >= N) return;
    const int lane = threadIdx.x & 63;
    const int d0 = lane * 2;
    const int s = off[c], e = off[c + 1];
    float ax = bias[d0], ay = bias[d0 + 1];
    int k = s;
    for (; k + 8 <= e; k += 8) {
        int r[8];
#pragma unroll
        for (int j = 0; j < 8; ++j) r[j] = eidx[k + j];
        f16x2 h[8];
        float w[8];
#pragma unroll
        for (int j = 0; j < 8; ++j) {
            h[j] = *(const f16x2*)&Hh[(size_t)r[j] * D + d0];
            w[j] = enrm[k + j];
        }
#pragma unroll
        for (int j = 0; j < 8; ++j) {
            ax += (float)h[j][0] * w[j];
            ay += (float)h[j][1] * w[j];
        }
    }
    for (; k < e; ++k) {
        f16x2 h = *(const f16x2*)&Hh[(size_t)eidx[k] * D + d0];
        float w = enrm[k];
        ax += (float)h[0] * w;
        ay += (float)h[1] * w;
    }
    float2 o;
    o.x = fmaxf(ax, 0.f);
    o.y = fmaxf(ay, 0.f);
    *(float2*)&O[(size_t)c * D + d0] = o;
}

// ----------------------------------------------------------------- head GEMV
__global__ __launch_bounds__(256) void head_kernel(const float* __restrict__ H,
                                                   const float* __restrict__ Wh,
                                                   const float* __restrict__ bh,
                                                   float* __restrict__ out, int N) {
    int gt = blockIdx.x * blockDim.x + threadIdx.x;
    int wid = gt >> 6;
    int lane = gt & 63;
    if (wid >= N) return;
    const float* hrow = H + (size_t)wid * D;
    float x0 = hrow[lane], x1 = hrow[lane + 64];
    float a0 = x0 * Wh[lane * 3 + 0] + x1 * Wh[(lane + 64) * 3 + 0];
    float a1 = x0 * Wh[lane * 3 + 1] + x1 * Wh[(lane + 64) * 3 + 1];
    float a2 = x0 * Wh[lane * 3 + 2] + x1 * Wh[(lane + 64) * 3 + 2];
#pragma unroll
    for (int s = 32; s > 0; s >>= 1) {
        a0 += __shfl_down(a0, s);
        a1 += __shfl_down(a1, s);
        a2 += __shfl_down(a2, s);
    }
    if (lane == 0) {
        out[wid * 3 + 0] = a0 + bh[0];
        out[wid * 3 + 1] = a1 + bh[1];
        out[wid * 3 + 2] = a2 + bh[2];
    }
}

// ---------------------------------------------------------------------------
extern "C" void kernel_launch(void* const* d_in, const int* in_sizes, int n_in,
                              void* d_out, int out_size, void* d_ws, size_t ws_size,
                              hipStream_t stream) {
    const float* x  = (const float*)d_in[0];
    const int*   ei = (const int*)d_in[1];
    const float* W1 = (const float*)d_in[2];
    const float* b1 = (const float*)d_in[3];
    const float* W2 = (const float*)d_in[4];
    const float* b2 = (const float*)d_in[5];
    const float* Wh = (const float*)d_in[6];
    const float* bh = (const float*)d_in[7];
    float* out = (float*)d_out;

    const int N = in_sizes[0] / D;       // 50000
    const int E = in_sizes[1] / 2;       // 800000
    const int Etot = E + N;
    const int* row = ei;
    const int* col = ei + E;

    // -------- workspace layout
    char* ws = (char*)d_ws;
    size_t o = 0;
    auto alloc = [&](size_t bytes) -> char* {
        char* p = ws + o;
        o = (o + bytes + 255) & ~(size_t)255;
        return p;
    };
    const int nb = (N + 255) / 256;
    int*   cnt    = (int*)  alloc((size_t)N * 4);
    int*   off    = (int*)  alloc((size_t)(N + 1) * 4);
    int*   cursor = (int*)  alloc((size_t)N * 4);
    float* dis    = (float*)alloc((size_t)N * 4);
    int*   bsum   = (int*)  alloc((size_t)nb * 4);
    int*   boff   = (int*)  alloc((size_t)nb * 4);
    int*   eidx   = (int*)  alloc((size_t)Etot * 4);
    float* enrm   = (float*)alloc((size_t)Etot * 4);
    f16*   W1t    = (f16*)  alloc((size_t)128 * 128 * 2);
    f16*   W2t    = (f16*)  alloc((size_t)128 * 128 * 2);
    f16*   Hh     = (f16*)  alloc((size_t)N * D * 2);   // gather matrix (fp16)
    float* B      = (float*)alloc((size_t)N * D * 4);   // conv output (f32)
    (void)ws_size;

    hipMemsetAsync(cnt, 0, (size_t)N * 4, stream);
    count_edges<<<(E + 255) / 256, 256, 0, stream>>>(col, cnt, E);
    scan_partial<<<nb, 256, 0, stream>>>(cnt, dis, bsum, N);
    scan_blocksums<<<1, 256, 0, stream>>>(bsum, boff, nb);
    scan_final<<<nb, 256, 0, stream>>>(cnt, boff, off, cursor, N, Etot);
    fill_edges<<<(Etot + 255) / 256, 256, 0, stream>>>(row, col, dis, cursor,
                                                       eidx, enrm, E, N);
    transpose_w<<<2, 1024, 0, stream>>>(W1, W2, W1t, W2t);

    const int gblocks = (N + 63) / 64;   // 64 rows per block (4 waves x 16)
    const int sblocks = (N + 3) / 4;     // 4 targets per block
    gemm_mfma<<<gblocks, 256, 0, stream>>>(x, W1t, Hh, N);
    spmm_row<<<sblocks, 256, 0, stream>>>(Hh, off, eidx, enrm, b1, B, N);
    gemm_mfma<<<gblocks, 256, 0, stream>>>(B, W2t, Hh, N);
    spmm_row<<<sblocks, 256, 0, stream>>>(Hh, off, eidx, enrm, b2, B, N);
    head_kernel<<<((size_t)N * 64 + 255) / 256, 256, 0, stream>>>(B, Wh, bh, out, N);
}